// Round 1
// baseline (228.716 us; speedup 1.0000x reference)
//
#include <hip/hip_runtime.h>

// out[b,o,n] = max_d |x[b,d,n] - w[o,d]| + bias[o]
// B=64, CIN=1024, COUT=1024, N=49. Pixels P = B*N = 3136 = 49*64 (exact tiling).
// GEMM-style tiling: block = 64 pixels x 128 channels, K-step 32, 256 threads,
// per-thread 4x8 register tile. Inner op written as fmaxf(fmaxf(acc,|d0|),|d1|)
// to encourage v_max3_f32 with abs source modifiers (1.5 instr/update).

#define TB 256
#define MP 64
#define NOC 128
#define KT 32

constexpr int CIN  = 1024;
constexpr int COUT = 1024;
constexpr int NN   = 49;
constexpr int BB   = 64;
constexpr int P    = BB * NN;  // 3136

__global__ __launch_bounds__(TB) void ndist_kernel(
    const float* __restrict__ x, const float* __restrict__ w,
    const float* __restrict__ bias, float* __restrict__ out)
{
    __shared__ float xs[KT][MP];    // 8 KB
    __shared__ float ws[KT][NOC];   // 16 KB

    const int t  = threadIdx.x;
    const int p0 = blockIdx.x * MP;   // pixel tile base
    const int c0 = blockIdx.y * NOC;  // channel tile base
    const int tp = t & 15;            // pixel group  -> pixels 4*tp..4*tp+3
    const int tc = t >> 4;            // channel group-> channels 8*tc..8*tc+7

    // Precompute x global offsets (k0 term added per K-step).
    // Loader: idx = t + i*TB over 2048 elems; kk = idx>>6, pp = idx&63.
    // Consecutive lanes -> consecutive pp -> (mostly) consecutive n: coalesced.
    int xoff[8];
#pragma unroll
    for (int i = 0; i < 8; ++i) {
        int idx = t + i * TB;
        int kk = idx >> 6, pp = idx & 63;
        int p = p0 + pp;
        int b = p / NN, n = p - b * NN;
        xoff[i] = (b * CIN + kk) * NN + n;
    }

    float acc[4][8];
#pragma unroll
    for (int i = 0; i < 4; ++i)
#pragma unroll
        for (int j = 0; j < 8; ++j) acc[i][j] = 0.0f;  // |diff| >= 0, identity ok

    for (int k0 = 0; k0 < CIN; k0 += KT) {
        // stage x tile [KT][MP]: 2048 floats, 8 scalar loads/thread, coalesced
#pragma unroll
        for (int i = 0; i < 8; ++i) {
            int idx = t + i * TB;
            xs[idx >> 6][idx & 63] = x[xoff[i] + k0 * NN];
        }
        // stage w tile [KT][NOC]: 4096 floats via float4 along d (coalesced),
        // scattered LDS writes (stride NOC) -- tiny fraction of instrs, ok
#pragma unroll
        for (int i = 0; i < 4; ++i) {
            int q = t + i * TB;
            int ch = q >> 3, kq = (q & 7) << 2;
            float4 wv = *reinterpret_cast<const float4*>(&w[(c0 + ch) * CIN + k0 + kq]);
            ws[kq + 0][ch] = wv.x;
            ws[kq + 1][ch] = wv.y;
            ws[kq + 2][ch] = wv.z;
            ws[kq + 3][ch] = wv.w;
        }
        __syncthreads();

#pragma unroll
        for (int kk = 0; kk < KT; kk += 2) {
            float xa[4], xb[4], wa[8], wb[8];
#pragma unroll
            for (int i = 0; i < 4; ++i) {
                xa[i] = xs[kk][4 * tp + i];       // -> ds_read_b128
                xb[i] = xs[kk + 1][4 * tp + i];
            }
#pragma unroll
            for (int j = 0; j < 8; ++j) {
                wa[j] = ws[kk][8 * tc + j];       // -> 2x ds_read_b128 (broadcast)
                wb[j] = ws[kk + 1][8 * tc + j];
            }
#pragma unroll
            for (int i = 0; i < 4; ++i)
#pragma unroll
                for (int j = 0; j < 8; ++j) {
                    float d0 = xa[i] - wa[j];
                    float d1 = xb[i] - wb[j];
                    // hope: v_max3_f32 acc, |d0|, |d1|
                    acc[i][j] = fmaxf(fmaxf(acc[i][j], __builtin_fabsf(d0)),
                                      __builtin_fabsf(d1));
                }
        }
        __syncthreads();
    }

    // epilogue: 32 scalar stores/thread + bias
#pragma unroll
    for (int i = 0; i < 4; ++i) {
        int p = p0 + 4 * tp + i;
        int b = p / NN, n = p - b * NN;
#pragma unroll
        for (int j = 0; j < 8; ++j) {
            int o = c0 + 8 * tc + j;
            out[(b * COUT + o) * NN + n] = acc[i][j] + bias[o];
        }
    }
}

extern "C" void kernel_launch(void* const* d_in, const int* in_sizes, int n_in,
                              void* d_out, int out_size, void* d_ws, size_t ws_size,
                              hipStream_t stream) {
    const float* x    = (const float*)d_in[0];
    const float* w    = (const float*)d_in[1];
    const float* bias = (const float*)d_in[2];
    float* out        = (float*)d_out;

    dim3 grid(P / MP, COUT / NOC);  // 49 x 8 = 392 blocks
    ndist_kernel<<<grid, TB, 0, stream>>>(x, w, bias, out);
}

// Round 2
// 150.818 us; speedup vs baseline: 1.5165x; 1.5165x over previous
//
#include <hip/hip_runtime.h>

// out[b,o,n] = max_d |x[b,d,n] - w[o,d]| + bias[o]
// B=64, CIN=1024, COUT=1024, N=49. Pixels P = B*N = 3136 = 49*64.
//
// Round-2 design: lane = pixel (64 pixels/wave, same pixels for all 4 waves
// of a block), each wave owns 8 output channels -> w[o][k] is wave-uniform ->
// scalar loads (s_load_dwordx8) on the scalar pipe; x streams into VGPRs.
// No LDS, no __syncthreads, ~30 VGPRs -> occupancy limited only by grid:
// 49 x 32 = 1568 blocks ~= 6.1 blocks/CU ~= 24 waves/CU.
// Inner op: v_subrev_f32 (s,v) x2 + v_max3_f32 acc,|d0|,|d1| = 1.5 instr/update.

constexpr int CIN  = 1024;
constexpr int COUT = 1024;
constexpr int NN   = 49;
constexpr int BB   = 64;
constexpr int P    = BB * NN;   // 3136
constexpr int CPW  = 8;         // channels per wave
constexpr int WPB  = 4;         // waves per block
constexpr int CPB  = CPW * WPB; // 32 channels per block
constexpr int KU   = 8;         // k unroll (matches s_load_dwordx8)

__global__ __launch_bounds__(256) void ndist_kernel(
    const float* __restrict__ x, const float* __restrict__ w,
    const float* __restrict__ bias, float* __restrict__ out)
{
    const int lane = threadIdx.x & 63;
    // Force wave-uniformity so the compiler scalarizes everything derived
    // from the wave id (w addresses -> s_load, bias -> s_load).
    const int wid  = __builtin_amdgcn_readfirstlane(threadIdx.x >> 6);

    const int p = blockIdx.x * BB + lane;    // pixel, exact (3136 = 49*64)
    const int b = p / NN;
    const int n = p - b * NN;
    const int o0 = blockIdx.y * CPB + wid * CPW;

    const float* __restrict__ xrow = x + (size_t)b * CIN * NN + n;

    float acc[CPW];
#pragma unroll
    for (int c = 0; c < CPW; ++c) acc[c] = 0.0f;   // |diff| >= 0, identity ok

    for (int k0 = 0; k0 < CIN; k0 += KU) {
        // 8 coalesced dword loads (stride 196 B -> immediate offsets off one base);
        // the 4 waves of the block read identical lines -> L1 broadcast.
        float xv[KU];
#pragma unroll
        for (int j = 0; j < KU; ++j) xv[j] = xrow[(k0 + j) * NN];

#pragma unroll
        for (int c = 0; c < CPW; ++c) {
            const float* __restrict__ wr = w + (size_t)(o0 + c) * CIN + k0;  // uniform
#pragma unroll
            for (int j = 0; j < KU; j += 2) {
                float d0 = xv[j]     - wr[j];      // v_subrev_f32 v, s, v
                float d1 = xv[j + 1] - wr[j + 1];
                acc[c] = fmaxf(fmaxf(acc[c], __builtin_fabsf(d0)),
                               __builtin_fabsf(d1));   // v_max3_f32 with |.| mods
            }
        }
    }

#pragma unroll
    for (int c = 0; c < CPW; ++c) {
        const int o = o0 + c;
        out[((size_t)b * COUT + o) * NN + n] = acc[c] + bias[o];  // bias: s_load
    }
}

extern "C" void kernel_launch(void* const* d_in, const int* in_sizes, int n_in,
                              void* d_out, int out_size, void* d_ws, size_t ws_size,
                              hipStream_t stream) {
    const float* x    = (const float*)d_in[0];
    const float* w    = (const float*)d_in[1];
    const float* bias = (const float*)d_in[2];
    float* out        = (float*)d_out;

    dim3 grid(P / BB, COUT / CPB);  // 49 x 32 = 1568 blocks
    ndist_kernel<<<grid, 256, 0, stream>>>(x, w, bias, out);
}